// Round 6
// baseline (763.839 us; speedup 1.0000x reference)
//
#include <hip/hip_runtime.h>
#include <hip/hip_bf16.h>
#include <math.h>

#define NNODES 50000
#define NEDGES 800000
#define HD     256   // HEADS*DHEAD
#define CW     384   // comb width: q(256) | qwe(64) | skip(64)
#define NTOT   896   // Wc rows: q(256)|qwe(64)|skip(64)|v(256)|k(256)
#define QS     0.18033688011112042f   // 0.125 * log2(e): fold softmax scale into exp2

typedef __hip_bfloat16 bf16;
typedef unsigned short u16;
typedef unsigned char  u8;
typedef unsigned int   u32;
typedef __attribute__((ext_vector_type(8))) short bf16x8;
typedef __attribute__((ext_vector_type(4))) float f32x4;
typedef __attribute__((ext_vector_type(2))) float f32x2;

__device__ __forceinline__ float lo16f(u32 u) { return __uint_as_float(u << 16); }
__device__ __forceinline__ float hi16f(u32 u) { return __uint_as_float(u & 0xFFFF0000u); }
__device__ __forceinline__ short f2s(float v) { __hip_bfloat16 h = __float2bfloat16(v); return *(short*)&h; }

// VALU cross-lane add within 16-lane groups
template<int CTRL>
__device__ __forceinline__ float dppadd(float x) {
    int t = __builtin_amdgcn_update_dpp(0, __float_as_int(x), CTRL, 0xF, 0xF, true);
    return x + __int_as_float(t);
}

// ---------------- CSR build ----------------
__global__ void hist_kernel(const int* __restrict__ dst, int* __restrict__ deg, int E) {
    int e = blockIdx.x * 256 + threadIdx.x;
    if (e < E) atomicAdd(&deg[dst[e]], 1);
}

__global__ void scanA(const int* __restrict__ deg, int* __restrict__ locincl,
                      int* __restrict__ blocksum, int n) {
    int tid = threadIdx.x;
    int i = blockIdx.x * 256 + tid;
    int v = (i < n) ? deg[i] : 0;
    int lane = tid & 63, w = tid >> 6;
    int s = v;
    #pragma unroll
    for (int off = 1; off < 64; off <<= 1) {
        int t = __shfl_up(s, off);
        if (lane >= off) s += t;
    }
    __shared__ int wsum[4];
    if (lane == 63) wsum[w] = s;
    __syncthreads();
    for (int ww = 0; ww < w; ww++) s += wsum[ww];
    if (i < n) locincl[i] = s;
    if (tid == 255) blocksum[blockIdx.x] = s;
}

__global__ void scanB(const int* __restrict__ blocksum, int* __restrict__ blockoff,
                      int nb, int* __restrict__ rowptr, int n) {
    int tid = threadIdx.x;
    int v = (tid < nb) ? blocksum[tid] : 0;
    int lane = tid & 63, w = tid >> 6;
    int s = v;
    #pragma unroll
    for (int off = 1; off < 64; off <<= 1) {
        int t = __shfl_up(s, off);
        if (lane >= off) s += t;
    }
    __shared__ int wsum[4];
    if (lane == 63) wsum[w] = s;
    __syncthreads();
    for (int ww = 0; ww < w; ww++) s += wsum[ww];
    if (tid < nb) blockoff[tid] = s - v;
    if (tid == 255) rowptr[n] = s;
}

__global__ void scanC(const int* __restrict__ deg, const int* __restrict__ locincl,
                      const int* __restrict__ blockoff,
                      int* __restrict__ rowptr, int* __restrict__ cursor, int n) {
    int i = blockIdx.x * 256 + threadIdx.x;
    if (i < n) {
        int ex = locincl[i] - deg[i] + blockoff[blockIdx.x];
        rowptr[i] = ex;
        cursor[i] = ex;
    }
}

__global__ void scatter_kernel(const int* __restrict__ src, const int* __restrict__ dst,
                               int* __restrict__ cursor, int2* __restrict__ csr2, int E) {
    int e = blockIdx.x * 256 + threadIdx.x;
    if (e < E) {
        int d = dst[e];
        int p = atomicAdd(&cursor[d], 1);
        csr2[p] = make_int2(src[e], e);
    }
}

// ---- x fp32 -> bf16 (once) ----
__global__ void xcast(const float* __restrict__ x, u16* __restrict__ xb) {
    int i = blockIdx.x * 256 + threadIdx.x;   // 3125 blocks x 256 x 8 elems = 6.4M exact
    const float4* p = (const float4*)(x + (size_t)i * 8);
    float4 a = p[0], b = p[1];
    union { u16 s[8]; uint4 u; } t;
    t.s[0] = (u16)f2s(a.x); t.s[1] = (u16)f2s(a.y); t.s[2] = (u16)f2s(a.z); t.s[3] = (u16)f2s(a.w);
    t.s[4] = (u16)f2s(b.x); t.s[5] = (u16)f2s(b.y); t.s[6] = (u16)f2s(b.z); t.s[7] = (u16)f2s(b.w);
    *(uint4*)(xb + (size_t)i * 8) = t.u;
}

// ---- pack: 896 rows n-major bf16 [NTOT][K] + fp32 bias ----
// rows: q(0..255)*QS | qwe(256..319)*QS | skip(320..383) | v(384..639) | k(640..895)
__global__ void pack_all(const float* __restrict__ Wq, const float* __restrict__ bq,
                         const float* __restrict__ Wk, const float* __restrict__ bk,
                         const float* __restrict__ Wv, const float* __restrict__ bv,
                         const float* __restrict__ We,
                         const float* __restrict__ Ws, const float* __restrict__ bs,
                         bf16* __restrict__ Wc, float* __restrict__ b, int K) {
    int n = blockIdx.x, c = threadIdx.x;
    float v, bb;
    if (n < 256)      { v = Wq[(size_t)c * 256 + n] * QS;    bb = bq[n] * QS; }
    else if (n < 320) {
        int t = n - 256, h = t >> 4, j = t & 15;
        float s = 0.f, sb = 0.f;
        #pragma unroll 8
        for (int d = 0; d < 64; d++) {
            float wv = We[j * HD + h * 64 + d];
            s += Wq[(size_t)c * 256 + h * 64 + d] * wv;
            sb += bq[h * 64 + d] * wv;
        }
        v = s * QS; bb = sb * QS;
    }
    else if (n < 384) { v = Ws[(size_t)c * 64  + (n - 320)]; bb = bs[n - 320]; }
    else if (n < 640) { v = Wv[(size_t)c * 256 + (n - 384)]; bb = bv[n - 384]; }
    else              { v = Wk[(size_t)c * 256 + (n - 640)]; bb = bk[n - 640]; }
    Wc[(size_t)n * K + c] = __float2bfloat16(v);
    if (c == 0) b[n] = bb;
}

// ---------------- MFMA GEMM, B-chunk resident in REGISTERS ----------------
// Grid (14, 98): blockIdx.x = chunk (64 output channels; B-frags loaded once into VGPRs,
// ~64 VGPR @K=128), blockIdx.y = m-slab of 512 rows (8 iters x 64). Zero LDS, zero
// barriers, zero global B-loads in the loop; A-frags register double-buffered.
template<int K>
__global__ void __launch_bounds__(256) gemm_reg(
    const u16* __restrict__ A, const bf16* __restrict__ Wc, const float* __restrict__ bias,
    bf16* __restrict__ comb, bf16* __restrict__ vbuf, u8* __restrict__ k8)
{
    constexpr int KS = K / 32;    // MFMA k-steps
    constexpr int ITERS = 8;
    int tid = threadIdx.x, w = tid >> 6, lane = tid & 63;
    int cl = lane & 15, aq = lane >> 4;
    int chunk = blockIdx.x;
    int mrow = blockIdx.y * (64 * ITERS) + w * 16 + cl;

    // B fragments for this chunk: rows chunk*64 + t*16 + cl, k-cols ks*32 + aq*8
    bf16x8 bfr[4][KS];
    #pragma unroll
    for (int t = 0; t < 4; t++)
        #pragma unroll
        for (int ks = 0; ks < KS; ks++)
            bfr[t][ks] = *(const bf16x8*)((const u16*)Wc +
                         (size_t)(chunk * 64 + t * 16 + cl) * K + ks * 32 + aq * 8);

    float4 bv[4];
    #pragma unroll
    for (int t = 0; t < 4; t++) bv[t] = *(const float4*)&bias[chunk * 64 + t * 16 + aq * 4];

    auto LOADA = [&](bf16x8* af, int m) {
        int rc = (m < NNODES) ? m : (NNODES - 1);
        const u16* ar = A + (size_t)rc * K + aq * 8;
        #pragma unroll
        for (int ks = 0; ks < KS; ks++) af[ks] = *(const bf16x8*)(ar + ks * 32);
    };

    bf16x8 cur[KS], nxt[KS];
    LOADA(cur, mrow);
    #pragma unroll
    for (int it = 0; it < ITERS; it++) {
        int m = mrow + it * 64;
        if (it + 1 < ITERS) LOADA(nxt, m + 64);   // prefetch next A-tile
        f32x4 acc[4] = {};
        #pragma unroll
        for (int t = 0; t < 4; t++)
            #pragma unroll
            for (int ks = 0; ks < KS; ks++)
                acc[t] = __builtin_amdgcn_mfma_f32_16x16x32_bf16(bfr[t][ks], cur[ks], acc[t], 0, 0, 0);

        if (m < NNODES) {
            if (chunk < 10) {
                u16* dst = (chunk < 6) ? (u16*)comb + (size_t)m * CW + chunk * 64
                                       : (u16*)vbuf + (size_t)m * 256 + (chunk - 6) * 64;
                #pragma unroll
                for (int t = 0; t < 4; t++) {
                    u32 lo = (u32)(u16)f2s(acc[t][0] + bv[t].x) | ((u32)(u16)f2s(acc[t][1] + bv[t].y) << 16);
                    u32 hi = (u32)(u16)f2s(acc[t][2] + bv[t].z) | ((u32)(u16)f2s(acc[t][3] + bv[t].w) << 16);
                    *(uint2*)(dst + t * 16 + aq * 4) = make_uint2(lo, hi);
                }
            } else {
                u8* dst = k8 + (size_t)m * 256 + (chunk - 10) * 64;
                #pragma unroll
                for (int t = 0; t < 4; t++) {
                    u32 pk = __builtin_amdgcn_cvt_pk_fp8_f32(acc[t][0] + bv[t].x, acc[t][1] + bv[t].y, 0, false);
                    pk = __builtin_amdgcn_cvt_pk_fp8_f32(acc[t][2] + bv[t].z, acc[t][3] + bv[t].w, pk, true);
                    *(u32*)(dst + t * 16 + aq * 4) = pk;
                }
            }
        }
        #pragma unroll
        for (int ks = 0; ks < KS; ks++) cur[ks] = nxt[ks];
    }
}

// ---------------- fused edge-logit + node aggregation + epilogue ----------------
// TWO waves per node (contiguous half-split of the edge list) for 2x memory-level
// parallelism; 2 nodes per 256-block. Gathers stay saddr-form (readfirstlane bases).
__global__ void __launch_bounds__(256) node_fused(
    const int* __restrict__ rowptr, const int2* __restrict__ csr2,
    const float* __restrict__ eattr, const u16* __restrict__ comb,
    const u16* __restrict__ vbuf, const u8* __restrict__ k8,
    const float* __restrict__ We, const float* __restrict__ lng, const float* __restrict__ lnb,
    bf16* __restrict__ outB, float* __restrict__ outF)
{
    int tid = threadIdx.x, w = tid >> 6, lane = tid & 63;
    int n = blockIdx.x * 2 + (w >> 1);           // 25000 * 2 == NNODES exactly
    int half = w & 1;
    int hg = lane >> 4, j16 = lane & 15, coff = 4 * lane;
    __shared__ float sAV[4][256];
    __shared__ float sAE[4][64];
    __shared__ float sSS[4][4];

    const u16* crow = comb + (size_t)n * CW;
    uint2 qv = *(const uint2*)(crow + coff);     // q channels coff..coff+3 (pre-scaled by QS)
    float qf0 = lo16f(qv.x), qf1 = hi16f(qv.x), qf2 = lo16f(qv.y), qf3 = hi16f(qv.y);
    float qwe_r = __uint_as_float((u32)crow[256 + lane] << 16);   // qwe (pre-scaled)

    int e0 = __builtin_amdgcn_readfirstlane(rowptr[n]);
    int e1 = __builtin_amdgcn_readfirstlane(rowptr[n + 1]);
    int mid = e0 + ((e1 - e0 + 1) >> 1);
    int lo = half ? mid : e0;
    int hi = half ? e1 : mid;

    float ss = 0.f, av0 = 0.f, av1 = 0.f, av2 = 0.f, av3 = 0.f, ae = 0.f;
    u32 vo = (u32)coff * 2u;
    u32 eo = (u32)j16 * 4u;

    auto EDGE = [&](int2 me) {
        u32 s   = (u32)__builtin_amdgcn_readfirstlane(me.x);   // wave-uniform -> SGPR
        u32 eid = (u32)__builtin_amdgcn_readfirstlane(me.y);
        const char* kp = (const char*)k8    + ((size_t)s << 8);
        const char* vp = (const char*)vbuf  + ((size_t)s << 9);
        const char* ep = (const char*)eattr + ((size_t)eid << 6);
        u32   kw = *(const u32*)  (kp + coff);
        uint2 vw = *(const uint2*)(vp + vo);
        float ea = *(const float*)(ep + eo);
        f32x2 k01 = __builtin_amdgcn_cvt_pk_f32_fp8(kw, false);
        f32x2 k23 = __builtin_amdgcn_cvt_pk_f32_fp8(kw, true);
        float part = qf0 * k01[0] + qf1 * k01[1] + qf2 * k23[0] + qf3 * k23[1] + qwe_r * ea;
        part = dppadd<0xB1>(part);    // xor 1
        part = dppadd<0x4E>(part);    // xor 2
        part = dppadd<0x141>(part);   // xor 4 (row_half_mirror)
        part = dppadd<0x140>(part);   // xor 8 (row_mirror)
        float alpha = __builtin_amdgcn_exp2f(part);   // scale folded into q at pack time
        ss += alpha;
        ae += alpha * ea;
        av0 += alpha * lo16f(vw.x); av1 += alpha * hi16f(vw.x);
        av2 += alpha * lo16f(vw.y); av3 += alpha * hi16f(vw.y);
    };

    int i = lo;
    int2 c0 = make_int2(0, 0), c1 = c0, c2 = c0, c3 = c0;
    if (i + 3 < hi) { c0 = csr2[i]; c1 = csr2[i + 1]; c2 = csr2[i + 2]; c3 = csr2[i + 3]; }
    for (; i + 7 < hi; i += 4) {
        int2 p0 = csr2[i + 4], p1 = csr2[i + 5], p2 = csr2[i + 6], p3 = csr2[i + 7];
        EDGE(c0); EDGE(c1); EDGE(c2); EDGE(c3);
        c0 = p0; c1 = p1; c2 = p2; c3 = p3;
    }
    if (i + 3 < hi) { EDGE(c0); EDGE(c1); EDGE(c2); EDGE(c3); i += 4; }
    for (; i < hi; ++i) { int2 cc = csr2[i]; EDGE(cc); }

    // merge the two half-waves, then epilogue on the even wave of each pair
    *(float4*)&sAV[w][coff] = make_float4(av0, av1, av2, av3);
    sAE[w][lane] = ae;
    if (j16 == 0) sSS[w][hg] = ss;
    __syncthreads();

    if ((w & 1) == 0) {
        float inv[4];
        #pragma unroll
        for (int h = 0; h < 4; h++) {
            float S = sSS[w][h] + sSS[w + 1][h];
            inv[h] = (S > 0.f) ? 1.f / S : 0.f;
        }
        {
            float aet = (sAE[w][lane] + sAE[w + 1][lane]) * inv[hg];
            sAE[w][lane] = aet;      // same-wave LDS ops are ordered; no barrier needed
        }
        int d = lane;
        float val = 0.f;
        #pragma unroll
        for (int h = 0; h < 4; h++) {
            float AV = sAV[w][h * 64 + d] + sAV[w + 1][h * 64 + d];
            float xv = AV * inv[h];
            #pragma unroll
            for (int j = 0; j < 16; j++) xv += sAE[w][h * 16 + j] * We[j * HD + h * 64 + d];
            val += xv;
        }
        val = val * 0.25f + __uint_as_float((u32)crow[320 + d] << 16);   // head mean + skip

        float m = val;
        #pragma unroll
        for (int off = 1; off < 64; off <<= 1) m += __shfl_xor(m, off);
        m *= (1.f / 64.f);
        float diff = val - m;
        float vr = diff * diff;
        #pragma unroll
        for (int off = 1; off < 64; off <<= 1) vr += __shfl_xor(vr, off);
        vr *= (1.f / 64.f);
        float y = diff * rsqrtf(vr + 1e-5f) * lng[d] + lnb[d];
        float ge = 0.5f * y * (1.f + erff(y * 0.70710678118654752f));    // exact GELU
        if (outF) outF[(size_t)n * 64 + d] = ge;
        else      outB[(size_t)n * 64 + d] = __float2bfloat16(ge);
    }
}

extern "C" void kernel_launch(void* const* d_in, const int* in_sizes, int n_in,
                              void* d_out, int out_size, void* d_ws, size_t ws_size,
                              hipStream_t stream)
{
    const float* x     = (const float*)d_in[0];
    const int*   eidx  = (const int*)d_in[1];
    const float* eattr = (const float*)d_in[2];
    struct P { const float *Wq,*bq,*Wk,*bk,*Wv,*bv,*We,*Ws,*bs; };
    P p[3];
    for (int l = 0; l < 3; l++) {
        int base = 3 + l * 9;
        p[l].Wq = (const float*)d_in[base + 0]; p[l].bq = (const float*)d_in[base + 1];
        p[l].Wk = (const float*)d_in[base + 2]; p[l].bk = (const float*)d_in[base + 3];
        p[l].Wv = (const float*)d_in[base + 4]; p[l].bv = (const float*)d_in[base + 5];
        p[l].We = (const float*)d_in[base + 6];
        p[l].Ws = (const float*)d_in[base + 7]; p[l].bs = (const float*)d_in[base + 8];
    }
    const float* lng = (const float*)d_in[30];
    const float* lnb = (const float*)d_in[31];

    // Workspace: ~104 MB
    char* ws = (char*)d_ws;
    size_t off = 0;
    auto alloc = [&](size_t bytes) { void* pp = ws + off; off += (bytes + 255) & ~(size_t)255; return pp; };
    int*   rowptr   = (int*)  alloc((NNODES + 1) * 4);
    int*   cursor   = (int*)  alloc(NNODES * 4);
    int*   deg      = (int*)  alloc(NNODES * 4);
    int*   blocksum = (int*)  alloc(256 * 4);
    int*   blockoff = (int*)  alloc(256 * 4);
    int2*  csr2     = (int2*) alloc((size_t)NEDGES * 8);        // 6.4 MB
    bf16*  hbuf     = (bf16*) alloc((size_t)NNODES * 64 * 2);   // 6.4 MB
    u16*   xb       = (u16*)  alloc((size_t)NNODES * 128 * 2);  // 12.8 MB bf16 x
    bf16*  comb     = (bf16*) alloc((size_t)NNODES * CW * 2);   // 38.4 MB: q|qwe|skip
    bf16*  vbuf     = (bf16*) alloc((size_t)NNODES * 256 * 2);  // 25.6 MB: v (512-B rows)
    u8*    k8       = (u8*)   alloc((size_t)NNODES * 256);      // 12.8 MB fp8 k
    bf16*  Wc       = (bf16*) alloc((size_t)NTOT * 128 * 2);    // 229 KB
    float* b896     = (float*)alloc(NTOT * 4);
    (void)ws_size;

    const int* srcArr = eidx;           // edge_index[0]
    const int* dstArr = eidx + NEDGES;  // edge_index[1]

    // CSR build (multi-block scan) + x cast
    int NB = (NNODES + 255) / 256;
    (void)hipMemsetAsync(deg, 0, NNODES * 4, stream);
    hist_kernel<<<(NEDGES + 255) / 256, 256, 0, stream>>>(dstArr, deg, NEDGES);
    scanA<<<NB, 256, 0, stream>>>(deg, cursor, blocksum, NNODES);
    scanB<<<1, 256, 0, stream>>>(blocksum, blockoff, NB, rowptr, NNODES);
    scanC<<<NB, 256, 0, stream>>>(deg, cursor, blockoff, rowptr, cursor, NNODES);
    scatter_kernel<<<(NEDGES + 255) / 256, 256, 0, stream>>>(srcArr, dstArr, cursor, csr2, NEDGES);
    xcast<<<(NNODES * 128 / 8 + 255) / 256, 256, 0, stream>>>(x, xb);

    int NBY = (NNODES + 511) / 512;   // 98 m-slabs of 512 rows
    int fins[3] = {128, 64, 64};

    const u16* hin = xb;
    for (int l = 0; l < 3; l++) {
        int FIN = fins[l];
        pack_all<<<NTOT, FIN, 0, stream>>>(p[l].Wq, p[l].bq, p[l].Wk, p[l].bk,
                                           p[l].Wv, p[l].bv, p[l].We, p[l].Ws, p[l].bs,
                                           Wc, b896, FIN);
        if (l == 0) gemm_reg<128><<<dim3(14, NBY), 256, 0, stream>>>(hin, Wc, b896, comb, vbuf, k8);
        else        gemm_reg<64> <<<dim3(14, NBY), 256, 0, stream>>>(hin, Wc, b896, comb, vbuf, k8);
        node_fused<<<NNODES / 2, 256, 0, stream>>>(rowptr, csr2, eattr, (const u16*)comb,
            (const u16*)vbuf, k8, p[l].We, lng, lnb,
            (l == 2) ? nullptr : hbuf, (l == 2) ? (float*)d_out : nullptr);
        hin = (const u16*)hbuf;
    }
}

// Round 7
// 655.245 us; speedup vs baseline: 1.1657x; 1.1657x over previous
//
#include <hip/hip_runtime.h>
#include <hip/hip_bf16.h>
#include <math.h>

#define NNODES 50000
#define NEDGES 800000
#define HD     256   // HEADS*DHEAD
#define CW     384   // comb width: q(256) | qwe(64) | skip(64)
#define NTOT   896   // Wc rows: q(256)|qwe(64)|skip(64)|v(256)|k(256)
#define QS     0.18033688011112042f   // 0.125 * log2(e): fold softmax scale into exp2

typedef __hip_bfloat16 bf16;
typedef unsigned short u16;
typedef unsigned char  u8;
typedef unsigned int   u32;
typedef __attribute__((ext_vector_type(8))) short bf16x8;
typedef __attribute__((ext_vector_type(4))) float f32x4;
typedef __attribute__((ext_vector_type(2))) float f32x2;

__device__ __forceinline__ float lo16f(u32 u) { return __uint_as_float(u << 16); }
__device__ __forceinline__ float hi16f(u32 u) { return __uint_as_float(u & 0xFFFF0000u); }
__device__ __forceinline__ short f2s(float v) { __hip_bfloat16 h = __float2bfloat16(v); return *(short*)&h; }

// VALU cross-lane add within 16-lane groups
template<int CTRL>
__device__ __forceinline__ float dppadd(float x) {
    int t = __builtin_amdgcn_update_dpp(0, __float_as_int(x), CTRL, 0xF, 0xF, true);
    return x + __int_as_float(t);
}

// ---------------- CSR build ----------------
__global__ void hist_kernel(const int* __restrict__ dst, int* __restrict__ deg, int E) {
    int e = blockIdx.x * 256 + threadIdx.x;
    if (e < E) atomicAdd(&deg[dst[e]], 1);
}

__global__ void scanA(const int* __restrict__ deg, int* __restrict__ locincl,
                      int* __restrict__ blocksum, int n) {
    int tid = threadIdx.x;
    int i = blockIdx.x * 256 + tid;
    int v = (i < n) ? deg[i] : 0;
    int lane = tid & 63, w = tid >> 6;
    int s = v;
    #pragma unroll
    for (int off = 1; off < 64; off <<= 1) {
        int t = __shfl_up(s, off);
        if (lane >= off) s += t;
    }
    __shared__ int wsum[4];
    if (lane == 63) wsum[w] = s;
    __syncthreads();
    for (int ww = 0; ww < w; ww++) s += wsum[ww];
    if (i < n) locincl[i] = s;
    if (tid == 255) blocksum[blockIdx.x] = s;
}

__global__ void scanB(const int* __restrict__ blocksum, int* __restrict__ blockoff,
                      int nb, int* __restrict__ rowptr, int n) {
    int tid = threadIdx.x;
    int v = (tid < nb) ? blocksum[tid] : 0;
    int lane = tid & 63, w = tid >> 6;
    int s = v;
    #pragma unroll
    for (int off = 1; off < 64; off <<= 1) {
        int t = __shfl_up(s, off);
        if (lane >= off) s += t;
    }
    __shared__ int wsum[4];
    if (lane == 63) wsum[w] = s;
    __syncthreads();
    for (int ww = 0; ww < w; ww++) s += wsum[ww];
    if (tid < nb) blockoff[tid] = s - v;
    if (tid == 255) rowptr[n] = s;
}

__global__ void scanC(const int* __restrict__ deg, const int* __restrict__ locincl,
                      const int* __restrict__ blockoff,
                      int* __restrict__ rowptr, int* __restrict__ cursor, int n) {
    int i = blockIdx.x * 256 + threadIdx.x;
    if (i < n) {
        int ex = locincl[i] - deg[i] + blockoff[blockIdx.x];
        rowptr[i] = ex;
        cursor[i] = ex;
    }
}

__global__ void scatter_kernel(const int* __restrict__ src, const int* __restrict__ dst,
                               int* __restrict__ cursor, int2* __restrict__ csr2, int E) {
    int e = blockIdx.x * 256 + threadIdx.x;
    if (e < E) {
        int d = dst[e];
        int p = atomicAdd(&cursor[d], 1);
        csr2[p] = make_int2(src[e], e);
    }
}

// ---- x fp32 -> bf16 (once) ----
__global__ void xcast(const float* __restrict__ x, u16* __restrict__ xb) {
    int i = blockIdx.x * 256 + threadIdx.x;
    const float4* p = (const float4*)(x + (size_t)i * 8);
    float4 a = p[0], b = p[1];
    union { u16 s[8]; uint4 u; } t;
    t.s[0] = (u16)f2s(a.x); t.s[1] = (u16)f2s(a.y); t.s[2] = (u16)f2s(a.z); t.s[3] = (u16)f2s(a.w);
    t.s[4] = (u16)f2s(b.x); t.s[5] = (u16)f2s(b.y); t.s[6] = (u16)f2s(b.z); t.s[7] = (u16)f2s(b.w);
    *(uint4*)(xb + (size_t)i * 8) = t.u;
}

// ---- pack: 896 rows n-major bf16 [NTOT][K] + fp32 bias ----
// rows: q(0..255)*QS | qwe(256..319)*QS | skip(320..383) | v(384..639) | k(640..895)
__global__ void pack_all(const float* __restrict__ Wq, const float* __restrict__ bq,
                         const float* __restrict__ Wk, const float* __restrict__ bk,
                         const float* __restrict__ Wv, const float* __restrict__ bv,
                         const float* __restrict__ We,
                         const float* __restrict__ Ws, const float* __restrict__ bs,
                         bf16* __restrict__ Wc, float* __restrict__ b, int K) {
    int n = blockIdx.x, c = threadIdx.x;
    float v, bb;
    if (n < 256)      { v = Wq[(size_t)c * 256 + n] * QS;    bb = bq[n] * QS; }
    else if (n < 320) {
        int t = n - 256, h = t >> 4, j = t & 15;
        float s = 0.f, sb = 0.f;
        #pragma unroll 8
        for (int d = 0; d < 64; d++) {
            float wv = We[j * HD + h * 64 + d];
            s += Wq[(size_t)c * 256 + h * 64 + d] * wv;
            sb += bq[h * 64 + d] * wv;
        }
        v = s * QS; bb = sb * QS;
    }
    else if (n < 384) { v = Ws[(size_t)c * 64  + (n - 320)]; bb = bs[n - 320]; }
    else if (n < 640) { v = Wv[(size_t)c * 256 + (n - 384)]; bb = bv[n - 384]; }
    else              { v = Wk[(size_t)c * 256 + (n - 640)]; bb = bk[n - 640]; }
    Wc[(size_t)n * K + c] = __float2bfloat16(v);
    if (c == 0) b[n] = bb;
}

// ---------------- MFMA GEMM, B-chunk in registers, LDS-transposed full-line stores ----------
// Grid (14, 98): blockIdx.x = chunk (64 channels, B-frags in VGPRs), blockIdx.y = m-slab
// (512 rows, 8 iters x 64). Zero barriers (per-wave LDS scratch; same-wave DS is ordered).
// Stores: acc -> per-wave LDS transpose -> full 128-B row segments (full-line HBM writes).
// A-frags prefetched 2 deep to cover L2 latency.
template<int K>
__global__ void __launch_bounds__(256) gemm_reg(
    const u16* __restrict__ A, const bf16* __restrict__ Wc, const float* __restrict__ bias,
    bf16* __restrict__ comb, bf16* __restrict__ vbuf, u8* __restrict__ k8)
{
    constexpr int KS = K / 32;    // MFMA k-steps
    constexpr int ITERS = 8;
    __shared__ u8 TrB[4][2560];   // per-wave scratch: 16 rows x 160 B (bf16) / 80 B (fp8)
    int tid = threadIdx.x, w = tid >> 6, lane = tid & 63;
    int cl = lane & 15, aq = lane >> 4;
    int chunk = blockIdx.x;
    int slab = blockIdx.y * (64 * ITERS);
    int mrow = slab + w * 16 + cl;
    u8* myT = TrB[w];

    // B fragments for this chunk: rows chunk*64 + t*16 + cl, k-cols ks*32 + aq*8
    bf16x8 bfr[4][KS];
    #pragma unroll
    for (int t = 0; t < 4; t++)
        #pragma unroll
        for (int ks = 0; ks < KS; ks++)
            bfr[t][ks] = *(const bf16x8*)((const u16*)Wc +
                         (size_t)(chunk * 64 + t * 16 + cl) * K + ks * 32 + aq * 8);

    float4 bv[4];
    #pragma unroll
    for (int t = 0; t < 4; t++) bv[t] = *(const float4*)&bias[chunk * 64 + t * 16 + aq * 4];

    auto LOADA = [&](bf16x8* af, int m) {
        int rc = (m < NNODES) ? m : (NNODES - 1);
        const u16* ar = A + (size_t)rc * K + aq * 8;
        #pragma unroll
        for (int ks = 0; ks < KS; ks++) af[ks] = *(const bf16x8*)(ar + ks * 32);
    };

    bf16x8 b0[KS], b1[KS], b2[KS];
    LOADA(b0, mrow);
    LOADA(b1, mrow + 64);
    #pragma unroll
    for (int it = 0; it < ITERS; it++) {
        int m = mrow + it * 64;
        if (it + 2 < ITERS) LOADA(b2, m + 128);   // depth-2 prefetch
        f32x4 acc[4] = {};
        #pragma unroll
        for (int t = 0; t < 4; t++)
            #pragma unroll
            for (int ks = 0; ks < KS; ks++)
                acc[t] = __builtin_amdgcn_mfma_f32_16x16x32_bf16(bfr[t][ks], b0[ks], acc[t], 0, 0, 0);

        if (chunk < 10) {
            // bf16 out: LDS rows stride 160 B, write [cl][t*32+aq*8], read 8 rows/inst
            #pragma unroll
            for (int t = 0; t < 4; t++) {
                u32 lo = (u32)(u16)f2s(acc[t][0] + bv[t].x) | ((u32)(u16)f2s(acc[t][1] + bv[t].y) << 16);
                u32 hi = (u32)(u16)f2s(acc[t][2] + bv[t].z) | ((u32)(u16)f2s(acc[t][3] + bv[t].w) << 16);
                *(uint2*)(myT + cl * 160 + t * 32 + aq * 8) = make_uint2(lo, hi);
            }
            #pragma unroll
            for (int i = 0; i < 2; i++) {
                int r = i * 8 + (lane >> 3);
                uint4 vv = *(const uint4*)(myT + r * 160 + (lane & 7) * 16);
                int gr = slab + it * 64 + w * 16 + r;
                if (gr < NNODES) {
                    u16* dst = (chunk < 6) ? (u16*)comb + (size_t)gr * CW + chunk * 64
                                           : (u16*)vbuf + (size_t)gr * 256 + (chunk - 6) * 64;
                    *(uint4*)(dst + (lane & 7) * 8) = vv;
                }
            }
        } else {
            // fp8 out: LDS rows stride 80 B, 1 store inst covers 16 rows x 64 B
            #pragma unroll
            for (int t = 0; t < 4; t++) {
                u32 pk = __builtin_amdgcn_cvt_pk_fp8_f32(acc[t][0] + bv[t].x, acc[t][1] + bv[t].y, 0, false);
                pk = __builtin_amdgcn_cvt_pk_fp8_f32(acc[t][2] + bv[t].z, acc[t][3] + bv[t].w, pk, true);
                *(u32*)(myT + cl * 80 + (t * 4 + aq) * 4) = pk;
            }
            {
                int r = lane >> 2;
                uint4 vv = *(const uint4*)(myT + r * 80 + (lane & 3) * 16);
                int gr = slab + it * 64 + w * 16 + r;
                if (gr < NNODES)
                    *(uint4*)(k8 + (size_t)gr * 256 + (chunk - 10) * 64 + (lane & 3) * 16) = vv;
            }
        }
        #pragma unroll
        for (int ks = 0; ks < KS; ks++) { b0[ks] = b1[ks]; b1[ks] = b2[ks]; }
    }
}

// ---------------- fused edge-logit + node aggregation + epilogue ----------------
// One wave per node (4 nodes/block). Wave-uniform edge values forced into SGPRs via
// readfirstlane -> all three gathers are saddr-form loads. No barriers anywhere.
__global__ void __launch_bounds__(256) node_fused(
    const int* __restrict__ rowptr, const int2* __restrict__ csr2,
    const float* __restrict__ eattr, const u16* __restrict__ comb,
    const u16* __restrict__ vbuf, const u8* __restrict__ k8,
    const float* __restrict__ We, const float* __restrict__ lng, const float* __restrict__ lnb,
    bf16* __restrict__ outB, float* __restrict__ outF)
{
    int tid = threadIdx.x, w = tid >> 6, lane = tid & 63;
    int n = blockIdx.x * 4 + w;                  // 12500 * 4 == NNODES exactly
    int hg = lane >> 4, j16 = lane & 15, coff = 4 * lane;
    __shared__ float sAV[4][256];
    __shared__ float sAE[4][64];

    const u16* crow = comb + (size_t)n * CW;
    uint2 qv = *(const uint2*)(crow + coff);     // q channels coff..coff+3 (pre-scaled by QS)
    float qf0 = lo16f(qv.x), qf1 = hi16f(qv.x), qf2 = lo16f(qv.y), qf3 = hi16f(qv.y);
    float qwe_r = __uint_as_float((u32)crow[256 + lane] << 16);   // qwe (pre-scaled)

    int e0 = __builtin_amdgcn_readfirstlane(rowptr[n]);
    int e1 = __builtin_amdgcn_readfirstlane(rowptr[n + 1]);

    float ss = 0.f, av0 = 0.f, av1 = 0.f, av2 = 0.f, av3 = 0.f, ae = 0.f;
    u32 vo = (u32)coff * 2u;
    u32 eo = (u32)j16 * 4u;

    auto EDGE = [&](int2 me) {
        u32 s   = (u32)__builtin_amdgcn_readfirstlane(me.x);   // wave-uniform -> SGPR
        u32 eid = (u32)__builtin_amdgcn_readfirstlane(me.y);
        const char* kp = (const char*)k8    + ((size_t)s << 8);
        const char* vp = (const char*)vbuf  + ((size_t)s << 9);
        const char* ep = (const char*)eattr + ((size_t)eid << 6);
        u32   kw = *(const u32*)  (kp + coff);
        uint2 vw = *(const uint2*)(vp + vo);
        float ea = *(const float*)(ep + eo);
        f32x2 k01 = __builtin_amdgcn_cvt_pk_f32_fp8(kw, false);
        f32x2 k23 = __builtin_amdgcn_cvt_pk_f32_fp8(kw, true);
        float part = qf0 * k01[0] + qf1 * k01[1] + qf2 * k23[0] + qf3 * k23[1] + qwe_r * ea;
        part = dppadd<0xB1>(part);    // xor 1
        part = dppadd<0x4E>(part);    // xor 2
        part = dppadd<0x141>(part);   // xor 4 (row_half_mirror)
        part = dppadd<0x140>(part);   // xor 8 (row_mirror)
        float alpha = __builtin_amdgcn_exp2f(part);   // scale folded into q at pack time
        ss += alpha;
        ae += alpha * ea;
        av0 += alpha * lo16f(vw.x); av1 += alpha * hi16f(vw.x);
        av2 += alpha * lo16f(vw.y); av3 += alpha * hi16f(vw.y);
    };

    int i = e0;
    int2 c0 = make_int2(0, 0), c1 = c0, c2 = c0, c3 = c0;
    if (i + 3 < e1) { c0 = csr2[i]; c1 = csr2[i + 1]; c2 = csr2[i + 2]; c3 = csr2[i + 3]; }
    for (; i + 7 < e1; i += 4) {
        int2 p0 = csr2[i + 4], p1 = csr2[i + 5], p2 = csr2[i + 6], p3 = csr2[i + 7];
        EDGE(c0); EDGE(c1); EDGE(c2); EDGE(c3);
        c0 = p0; c1 = p1; c2 = p2; c3 = p3;
    }
    if (i + 3 < e1) { EDGE(c0); EDGE(c1); EDGE(c2); EDGE(c3); i += 4; }
    for (; i < e1; ++i) { int2 cc = csr2[i]; EDGE(cc); }

    // epilogue (all waves active; same-wave LDS transpose, no barrier)
    float inv = (ss > 0.f) ? 1.f / ss : 0.f;     // uniform within each 16-lane head group
    *(float4*)&sAV[w][coff] = make_float4(av0 * inv, av1 * inv, av2 * inv, av3 * inv);
    sAE[w][lane] = ae * inv;

    int d = lane;
    float val = 0.f;
    #pragma unroll
    for (int h = 0; h < 4; h++) {
        float xv = sAV[w][h * 64 + d];
        #pragma unroll
        for (int j = 0; j < 16; j++) xv += sAE[w][h * 16 + j] * We[j * HD + h * 64 + d];
        val += xv;
    }
    val = val * 0.25f + __uint_as_float((u32)crow[320 + d] << 16);   // head mean + skip

    float m = val;
    #pragma unroll
    for (int off = 1; off < 64; off <<= 1) m += __shfl_xor(m, off);
    m *= (1.f / 64.f);
    float diff = val - m;
    float vr = diff * diff;
    #pragma unroll
    for (int off = 1; off < 64; off <<= 1) vr += __shfl_xor(vr, off);
    vr *= (1.f / 64.f);
    float y = diff * rsqrtf(vr + 1e-5f) * lng[d] + lnb[d];
    float ge = 0.5f * y * (1.f + erff(y * 0.70710678118654752f));    // exact GELU
    if (outF) outF[(size_t)n * 64 + d] = ge;
    else      outB[(size_t)n * 64 + d] = __float2bfloat16(ge);
}

extern "C" void kernel_launch(void* const* d_in, const int* in_sizes, int n_in,
                              void* d_out, int out_size, void* d_ws, size_t ws_size,
                              hipStream_t stream)
{
    const float* x     = (const float*)d_in[0];
    const int*   eidx  = (const int*)d_in[1];
    const float* eattr = (const float*)d_in[2];
    struct P { const float *Wq,*bq,*Wk,*bk,*Wv,*bv,*We,*Ws,*bs; };
    P p[3];
    for (int l = 0; l < 3; l++) {
        int base = 3 + l * 9;
        p[l].Wq = (const float*)d_in[base + 0]; p[l].bq = (const float*)d_in[base + 1];
        p[l].Wk = (const float*)d_in[base + 2]; p[l].bk = (const float*)d_in[base + 3];
        p[l].Wv = (const float*)d_in[base + 4]; p[l].bv = (const float*)d_in[base + 5];
        p[l].We = (const float*)d_in[base + 6];
        p[l].Ws = (const float*)d_in[base + 7]; p[l].bs = (const float*)d_in[base + 8];
    }
    const float* lng = (const float*)d_in[30];
    const float* lnb = (const float*)d_in[31];

    // Workspace: ~104 MB
    char* ws = (char*)d_ws;
    size_t off = 0;
    auto alloc = [&](size_t bytes) { void* pp = ws + off; off += (bytes + 255) & ~(size_t)255; return pp; };
    int*   rowptr   = (int*)  alloc((NNODES + 1) * 4);
    int*   cursor   = (int*)  alloc(NNODES * 4);
    int*   deg      = (int*)  alloc(NNODES * 4);
    int*   blocksum = (int*)  alloc(256 * 4);
    int*   blockoff = (int*)  alloc(256 * 4);
    int2*  csr2     = (int2*) alloc((size_t)NEDGES * 8);        // 6.4 MB
    bf16*  hbuf     = (bf16*) alloc((size_t)NNODES * 64 * 2);   // 6.4 MB
    u16*   xb       = (u16*)  alloc((size_t)NNODES * 128 * 2);  // 12.8 MB bf16 x
    bf16*  comb     = (bf16*) alloc((size_t)NNODES * CW * 2);   // 38.4 MB: q|qwe|skip
    bf16*  vbuf     = (bf16*) alloc((size_t)NNODES * 256 * 2);  // 25.6 MB: v (512-B rows)
    u8*    k8       = (u8*)   alloc((size_t)NNODES * 256);      // 12.8 MB fp8 k
    bf16*  Wc       = (bf16*) alloc((size_t)NTOT * 128 * 2);    // 229 KB
    float* b896     = (float*)alloc(NTOT * 4);
    (void)ws_size;

    const int* srcArr = eidx;           // edge_index[0]
    const int* dstArr = eidx + NEDGES;  // edge_index[1]

    // CSR build (multi-block scan) + x cast
    int NB = (NNODES + 255) / 256;
    (void)hipMemsetAsync(deg, 0, NNODES * 4, stream);
    hist_kernel<<<(NEDGES + 255) / 256, 256, 0, stream>>>(dstArr, deg, NEDGES);
    scanA<<<NB, 256, 0, stream>>>(deg, cursor, blocksum, NNODES);
    scanB<<<1, 256, 0, stream>>>(blocksum, blockoff, NB, rowptr, NNODES);
    scanC<<<NB, 256, 0, stream>>>(deg, cursor, blockoff, rowptr, cursor, NNODES);
    scatter_kernel<<<(NEDGES + 255) / 256, 256, 0, stream>>>(srcArr, dstArr, cursor, csr2, NEDGES);
    xcast<<<(NNODES * 128 / 8 + 255) / 256, 256, 0, stream>>>(x, xb);

    int NBY = (NNODES + 511) / 512;   // 98 m-slabs of 512 rows
    int fins[3] = {128, 64, 64};

    const u16* hin = xb;
    for (int l = 0; l < 3; l++) {
        int FIN = fins[l];
        pack_all<<<NTOT, FIN, 0, stream>>>(p[l].Wq, p[l].bq, p[l].Wk, p[l].bk,
                                           p[l].Wv, p[l].bv, p[l].We, p[l].Ws, p[l].bs,
                                           Wc, b896, FIN);
        if (l == 0) gemm_reg<128><<<dim3(14, NBY), 256, 0, stream>>>(hin, Wc, b896, comb, vbuf, k8);
        else        gemm_reg<64> <<<dim3(14, NBY), 256, 0, stream>>>(hin, Wc, b896, comb, vbuf, k8);
        node_fused<<<NNODES / 4, 256, 0, stream>>>(rowptr, csr2, eattr, (const u16*)comb,
            (const u16*)vbuf, k8, p[l].We, lng, lnb,
            (l == 2) ? nullptr : hbuf, (l == 2) ? (float*)d_out : nullptr);
        hin = (const u16*)hbuf;
    }
}

// Round 8
// 654.237 us; speedup vs baseline: 1.1675x; 1.0015x over previous
//
#include <hip/hip_runtime.h>
#include <hip/hip_bf16.h>
#include <math.h>

#define NNODES 50000
#define NEDGES 800000
#define HD     256   // HEADS*DHEAD
#define CW     384   // comb width: q(256) | qwe(64) | skip(64)
#define NTOT   896   // Wc rows: q(256)|qwe(64)|skip(64)|v(256)|k(256)
#define QS     0.18033688011112042f   // 0.125 * log2(e): fold softmax scale into exp2

typedef __hip_bfloat16 bf16;
typedef unsigned short u16;
typedef unsigned char  u8;
typedef unsigned int   u32;
typedef __attribute__((ext_vector_type(8))) short bf16x8;
typedef __attribute__((ext_vector_type(4))) float f32x4;
typedef __attribute__((ext_vector_type(2))) float f32x2;

__device__ __forceinline__ float lo16f(u32 u) { return __uint_as_float(u << 16); }
__device__ __forceinline__ float hi16f(u32 u) { return __uint_as_float(u & 0xFFFF0000u); }
__device__ __forceinline__ short f2s(float v) { __hip_bfloat16 h = __float2bfloat16(v); return *(short*)&h; }

// async global->LDS, 16B per lane; lds dest is wave-uniform base + lane*16 (linear)
__device__ __forceinline__ void gload_lds16(const void* g, void* l) {
    __builtin_amdgcn_global_load_lds(
        (const __attribute__((address_space(1))) void*)g,
        (__attribute__((address_space(3))) void*)l, 16, 0, 0);
}

// VALU cross-lane add within 16-lane groups
template<int CTRL>
__device__ __forceinline__ float dppadd(float x) {
    int t = __builtin_amdgcn_update_dpp(0, __float_as_int(x), CTRL, 0xF, 0xF, true);
    return x + __int_as_float(t);
}

// ---------------- CSR build ----------------
__global__ void hist_kernel(const int* __restrict__ dst, int* __restrict__ deg, int E) {
    int e = blockIdx.x * 256 + threadIdx.x;
    if (e < E) atomicAdd(&deg[dst[e]], 1);
}

__global__ void scanA(const int* __restrict__ deg, int* __restrict__ locincl,
                      int* __restrict__ blocksum, int n) {
    int tid = threadIdx.x;
    int i = blockIdx.x * 256 + tid;
    int v = (i < n) ? deg[i] : 0;
    int lane = tid & 63, w = tid >> 6;
    int s = v;
    #pragma unroll
    for (int off = 1; off < 64; off <<= 1) {
        int t = __shfl_up(s, off);
        if (lane >= off) s += t;
    }
    __shared__ int wsum[4];
    if (lane == 63) wsum[w] = s;
    __syncthreads();
    for (int ww = 0; ww < w; ww++) s += wsum[ww];
    if (i < n) locincl[i] = s;
    if (tid == 255) blocksum[blockIdx.x] = s;
}

__global__ void scanB(const int* __restrict__ blocksum, int* __restrict__ blockoff,
                      int nb, int* __restrict__ rowptr, int n) {
    int tid = threadIdx.x;
    int v = (tid < nb) ? blocksum[tid] : 0;
    int lane = tid & 63, w = tid >> 6;
    int s = v;
    #pragma unroll
    for (int off = 1; off < 64; off <<= 1) {
        int t = __shfl_up(s, off);
        if (lane >= off) s += t;
    }
    __shared__ int wsum[4];
    if (lane == 63) wsum[w] = s;
    __syncthreads();
    for (int ww = 0; ww < w; ww++) s += wsum[ww];
    if (tid < nb) blockoff[tid] = s - v;
    if (tid == 255) rowptr[n] = s;
}

__global__ void scanC(const int* __restrict__ deg, const int* __restrict__ locincl,
                      const int* __restrict__ blockoff,
                      int* __restrict__ rowptr, int* __restrict__ cursor, int n) {
    int i = blockIdx.x * 256 + threadIdx.x;
    if (i < n) {
        int ex = locincl[i] - deg[i] + blockoff[blockIdx.x];
        rowptr[i] = ex;
        cursor[i] = ex;
    }
}

__global__ void scatter_kernel(const int* __restrict__ src, const int* __restrict__ dst,
                               int* __restrict__ cursor, int2* __restrict__ csr2, int E) {
    int e = blockIdx.x * 256 + threadIdx.x;
    if (e < E) {
        int d = dst[e];
        int p = atomicAdd(&cursor[d], 1);
        csr2[p] = make_int2(src[e], e);
    }
}

// ---- x fp32 -> bf16 (once) ----
__global__ void xcast(const float* __restrict__ x, u16* __restrict__ xb) {
    int i = blockIdx.x * 256 + threadIdx.x;
    const float4* p = (const float4*)(x + (size_t)i * 8);
    float4 a = p[0], b = p[1];
    union { u16 s[8]; uint4 u; } t;
    t.s[0] = (u16)f2s(a.x); t.s[1] = (u16)f2s(a.y); t.s[2] = (u16)f2s(a.z); t.s[3] = (u16)f2s(a.w);
    t.s[4] = (u16)f2s(b.x); t.s[5] = (u16)f2s(b.y); t.s[6] = (u16)f2s(b.z); t.s[7] = (u16)f2s(b.w);
    *(uint4*)(xb + (size_t)i * 8) = t.u;
}

// ---- pack: 896 rows n-major bf16 [NTOT][K] + fp32 bias ----
// rows: q(0..255)*QS | qwe(256..319)*QS | skip(320..383) | v(384..639) | k(640..895)
__global__ void pack_all(const float* __restrict__ Wq, const float* __restrict__ bq,
                         const float* __restrict__ Wk, const float* __restrict__ bk,
                         const float* __restrict__ Wv, const float* __restrict__ bv,
                         const float* __restrict__ We,
                         const float* __restrict__ Ws, const float* __restrict__ bs,
                         bf16* __restrict__ Wc, float* __restrict__ b, int K) {
    int n = blockIdx.x, c = threadIdx.x;
    float v, bb;
    if (n < 256)      { v = Wq[(size_t)c * 256 + n] * QS;    bb = bq[n] * QS; }
    else if (n < 320) {
        int t = n - 256, h = t >> 4, j = t & 15;
        float s = 0.f, sb = 0.f;
        #pragma unroll 8
        for (int d = 0; d < 64; d++) {
            float wv = We[j * HD + h * 64 + d];
            s += Wq[(size_t)c * 256 + h * 64 + d] * wv;
            sb += bq[h * 64 + d] * wv;
        }
        v = s * QS; bb = sb * QS;
    }
    else if (n < 384) { v = Ws[(size_t)c * 64  + (n - 320)]; bb = bs[n - 320]; }
    else if (n < 640) { v = Wv[(size_t)c * 256 + (n - 384)]; bb = bv[n - 384]; }
    else              { v = Wk[(size_t)c * 256 + (n - 640)]; bb = bk[n - 640]; }
    Wc[(size_t)n * K + c] = __float2bfloat16(v);
    if (c == 0) b[n] = bb;
}

// ---------------- MFMA GEMM v4: coalesced A via global_load_lds, B in regs --------------
// Grid (14, 196): blockIdx.x = chunk (64 channels; B-frags gathered once into VGPRs),
// blockIdx.y = m-slab (4 tiles x 64 rows). Per tile: stage next A-tile (coalesced,
// source-swizzled) -> ds_read_b128 A-frags (swizzled, ~conflict-free) -> MFMA ->
// LDS-transposed full-line stores -> one __syncthreads (drains stage).
template<int K>
__global__ void __launch_bounds__(256) gemm_v4(
    const u16* __restrict__ A, const bf16* __restrict__ Wc, const float* __restrict__ bias,
    bf16* __restrict__ comb, bf16* __restrict__ vbuf, u8* __restrict__ k8)
{
    constexpr int KS    = K / 32;        // MFMA k-steps
    constexpr int ITERS = 4;
    constexpr int ROWB  = K * 2;         // bytes per A row
    constexpr int TILEB = 64 * ROWB;     // A-tile bytes (8 KB / 16 KB)
    constexpr int WSEG  = TILEB / 4;     // bytes staged per wave
    constexpr int NINST = WSEG / 1024;   // global_load_lds insts per wave (2 or 4)
    __shared__ __align__(16) u8 Ab[2][TILEB];
    __shared__ __align__(16) u8 TrB[4][2560];
    int tid = threadIdx.x, w = tid >> 6, lane = tid & 63;
    int cl = lane & 15, aq = lane >> 4;
    int chunk = blockIdx.x;
    int slab = blockIdx.y * (64 * ITERS);
    u8* myT = TrB[w];

    // B fragments for this chunk (gathered once; Wc is 229 KB, L2-hot)
    bf16x8 bfr[4][KS];
    #pragma unroll
    for (int t = 0; t < 4; t++)
        #pragma unroll
        for (int ks = 0; ks < KS; ks++)
            bfr[t][ks] = *(const bf16x8*)((const u16*)Wc +
                         (size_t)(chunk * 64 + t * 16 + cl) * K + ks * 32 + aq * 8);

    float4 bv[4];
    #pragma unroll
    for (int t = 0; t < 4; t++) bv[t] = *(const float4*)&bias[chunk * 64 + t * 16 + aq * 4];

    // stage tile 'it' into Ab[b]: linear LDS dest, inverse-swizzled global source
    auto STAGE = [&](int b, int it) {
        int m0 = slab + it * 64;
        #pragma unroll
        for (int i = 0; i < NINST; i++) {
            int off = w * WSEG + i * 1024;           // wave-uniform inst base in tile
            int rowbase = off / ROWB;
            int row, gran;
            if constexpr (K == 64) { row = rowbase + (lane >> 3); gran = lane & 7;  }
            else                   { row = rowbase + (lane >> 4); gran = lane & 15; }
            int gr = m0 + row; if (gr >= NNODES) gr = NNODES - 1;
            int sg = gran ^ (row & 7);               // inverse swizzle on SOURCE
            gload_lds16((const u8*)A + (size_t)gr * ROWB + sg * 16, Ab[b] + off);
        }
    };

    STAGE(0, 0);
    __syncthreads();
    int cur = 0;
    #pragma unroll
    for (int it = 0; it < ITERS; it++) {
        if (it + 1 < ITERS) STAGE(cur ^ 1, it + 1);   // issue next-tile loads (async)

        int rowt = w * 16 + cl;
        bf16x8 a[KS];
        #pragma unroll
        for (int ks = 0; ks < KS; ks++)               // swizzled ds_read_b128
            a[ks] = *(const bf16x8*)&Ab[cur][rowt * ROWB + (((ks * 4 + aq) ^ (rowt & 7)) << 4)];

        f32x4 acc[4] = {};
        #pragma unroll
        for (int t = 0; t < 4; t++)
            #pragma unroll
            for (int ks = 0; ks < KS; ks++)
                acc[t] = __builtin_amdgcn_mfma_f32_16x16x32_bf16(bfr[t][ks], a[ks], acc[t], 0, 0, 0);

        if (chunk < 10) {
            // bf16 out: per-wave LDS transpose (rows stride 160 B) -> full-line stores
            #pragma unroll
            for (int t = 0; t < 4; t++) {
                u32 lo = (u32)(u16)f2s(acc[t][0] + bv[t].x) | ((u32)(u16)f2s(acc[t][1] + bv[t].y) << 16);
                u32 hi = (u32)(u16)f2s(acc[t][2] + bv[t].z) | ((u32)(u16)f2s(acc[t][3] + bv[t].w) << 16);
                *(uint2*)(myT + cl * 160 + t * 32 + aq * 8) = make_uint2(lo, hi);
            }
            #pragma unroll
            for (int i = 0; i < 2; i++) {
                int r = i * 8 + (lane >> 3);
                uint4 vv = *(const uint4*)(myT + r * 160 + (lane & 7) * 16);
                int gr = slab + it * 64 + w * 16 + r;
                if (gr < NNODES) {
                    u16* dst = (chunk < 6) ? (u16*)comb + (size_t)gr * CW + chunk * 64
                                           : (u16*)vbuf + (size_t)gr * 256 + (chunk - 6) * 64;
                    *(uint4*)(dst + (lane & 7) * 8) = vv;
                }
            }
        } else {
            // fp8 out: rows stride 80 B; one inst covers 16 rows x 64 B
            #pragma unroll
            for (int t = 0; t < 4; t++) {
                u32 pk = __builtin_amdgcn_cvt_pk_fp8_f32(acc[t][0] + bv[t].x, acc[t][1] + bv[t].y, 0, false);
                pk = __builtin_amdgcn_cvt_pk_fp8_f32(acc[t][2] + bv[t].z, acc[t][3] + bv[t].w, pk, true);
                *(u32*)(myT + cl * 80 + (t * 4 + aq) * 4) = pk;
            }
            {
                int r = lane >> 2;
                uint4 vv = *(const uint4*)(myT + r * 80 + (lane & 3) * 16);
                int gr = slab + it * 64 + w * 16 + r;
                if (gr < NNODES)
                    *(uint4*)(k8 + (size_t)gr * 256 + (chunk - 10) * 64 + (lane & 3) * 16) = vv;
            }
        }
        __syncthreads();      // drains next-tile stage (vmcnt 0) + barrier
        cur ^= 1;
    }
}

// ---------------- fused edge-logit + node aggregation + epilogue ----------------
// One wave per node (4 nodes/block). Wave-uniform edge values forced into SGPRs via
// readfirstlane -> all three gathers are saddr-form loads. No barriers anywhere.
__global__ void __launch_bounds__(256) node_fused(
    const int* __restrict__ rowptr, const int2* __restrict__ csr2,
    const float* __restrict__ eattr, const u16* __restrict__ comb,
    const u16* __restrict__ vbuf, const u8* __restrict__ k8,
    const float* __restrict__ We, const float* __restrict__ lng, const float* __restrict__ lnb,
    bf16* __restrict__ outB, float* __restrict__ outF)
{
    int tid = threadIdx.x, w = tid >> 6, lane = tid & 63;
    int n = blockIdx.x * 4 + w;                  // 12500 * 4 == NNODES exactly
    int hg = lane >> 4, j16 = lane & 15, coff = 4 * lane;
    __shared__ float sAV[4][256];
    __shared__ float sAE[4][64];

    const u16* crow = comb + (size_t)n * CW;
    uint2 qv = *(const uint2*)(crow + coff);     // q channels coff..coff+3 (pre-scaled by QS)
    float qf0 = lo16f(qv.x), qf1 = hi16f(qv.x), qf2 = lo16f(qv.y), qf3 = hi16f(qv.y);
    float qwe_r = __uint_as_float((u32)crow[256 + lane] << 16);   // qwe (pre-scaled)

    int e0 = __builtin_amdgcn_readfirstlane(rowptr[n]);
    int e1 = __builtin_amdgcn_readfirstlane(rowptr[n + 1]);

    float ss = 0.f, av0 = 0.f, av1 = 0.f, av2 = 0.f, av3 = 0.f, ae = 0.f;
    u32 vo = (u32)coff * 2u;
    u32 eo = (u32)j16 * 4u;

    auto EDGE = [&](int2 me) {
        u32 s   = (u32)__builtin_amdgcn_readfirstlane(me.x);   // wave-uniform -> SGPR
        u32 eid = (u32)__builtin_amdgcn_readfirstlane(me.y);
        const char* kp = (const char*)k8    + ((size_t)s << 8);
        const char* vp = (const char*)vbuf  + ((size_t)s << 9);
        const char* ep = (const char*)eattr + ((size_t)eid << 6);
        u32   kw = *(const u32*)  (kp + coff);
        uint2 vw = *(const uint2*)(vp + vo);
        float ea = *(const float*)(ep + eo);
        f32x2 k01 = __builtin_amdgcn_cvt_pk_f32_fp8(kw, false);
        f32x2 k23 = __builtin_amdgcn_cvt_pk_f32_fp8(kw, true);
        float part = qf0 * k01[0] + qf1 * k01[1] + qf2 * k23[0] + qf3 * k23[1] + qwe_r * ea;
        part = dppadd<0xB1>(part);    // xor 1
        part = dppadd<0x4E>(part);    // xor 2
        part = dppadd<0x141>(part);   // xor 4 (row_half_mirror)
        part = dppadd<0x140>(part);   // xor 8 (row_mirror)
        float alpha = __builtin_amdgcn_exp2f(part);   // scale folded into q at pack time
        ss += alpha;
        ae += alpha * ea;
        av0 += alpha * lo16f(vw.x); av1 += alpha * hi16f(vw.x);
        av2 += alpha * lo16f(vw.y); av3 += alpha * hi16f(vw.y);
    };

    int i = e0;
    int2 c0 = make_int2(0, 0), c1 = c0, c2 = c0, c3 = c0;
    if (i + 3 < e1) { c0 = csr2[i]; c1 = csr2[i + 1]; c2 = csr2[i + 2]; c3 = csr2[i + 3]; }
    for (; i + 7 < e1; i += 4) {
        int2 p0 = csr2[i + 4], p1 = csr2[i + 5], p2 = csr2[i + 6], p3 = csr2[i + 7];
        EDGE(c0); EDGE(c1); EDGE(c2); EDGE(c3);
        c0 = p0; c1 = p1; c2 = p2; c3 = p3;
    }
    if (i + 3 < e1) { EDGE(c0); EDGE(c1); EDGE(c2); EDGE(c3); i += 4; }
    for (; i < e1; ++i) { int2 cc = csr2[i]; EDGE(cc); }

    // epilogue (all waves active; same-wave LDS transpose, no barrier)
    float inv = (ss > 0.f) ? 1.f / ss : 0.f;     // uniform within each 16-lane head group
    *(float4*)&sAV[w][coff] = make_float4(av0 * inv, av1 * inv, av2 * inv, av3 * inv);
    sAE[w][lane] = ae * inv;

    int d = lane;
    float val = 0.f;
    #pragma unroll
    for (int h = 0; h < 4; h++) {
        float xv = sAV[w][h * 64 + d];
        #pragma unroll
        for (int j = 0; j < 16; j++) xv += sAE[w][h * 16 + j] * We[j * HD + h * 64 + d];
        val += xv;
    }
    val = val * 0.25f + __uint_as_float((u32)crow[320 + d] << 16);   // head mean + skip

    float m = val;
    #pragma unroll
    for (int off = 1; off < 64; off <<= 1) m += __shfl_xor(m, off);
    m *= (1.f / 64.f);
    float diff = val - m;
    float vr = diff * diff;
    #pragma unroll
    for (int off = 1; off < 64; off <<= 1) vr += __shfl_xor(vr, off);
    vr *= (1.f / 64.f);
    float y = diff * rsqrtf(vr + 1e-5f) * lng[d] + lnb[d];
    float ge = 0.5f * y * (1.f + erff(y * 0.70710678118654752f));    // exact GELU
    if (outF) outF[(size_t)n * 64 + d] = ge;
    else      outB[(size_t)n * 64 + d] = __float2bfloat16(ge);
}

extern "C" void kernel_launch(void* const* d_in, const int* in_sizes, int n_in,
                              void* d_out, int out_size, void* d_ws, size_t ws_size,
                              hipStream_t stream)
{
    const float* x     = (const float*)d_in[0];
    const int*   eidx  = (const int*)d_in[1];
    const float* eattr = (const float*)d_in[2];
    struct P { const float *Wq,*bq,*Wk,*bk,*Wv,*bv,*We,*Ws,*bs; };
    P p[3];
    for (int l = 0; l < 3; l++) {
        int base = 3 + l * 9;
        p[l].Wq = (const float*)d_in[base + 0]; p[l].bq = (const float*)d_in[base + 1];
        p[l].Wk = (const float*)d_in[base + 2]; p[l].bk = (const float*)d_in[base + 3];
        p[l].Wv = (const float*)d_in[base + 4]; p[l].bv = (const float*)d_in[base + 5];
        p[l].We = (const float*)d_in[base + 6];
        p[l].Ws = (const float*)d_in[base + 7]; p[l].bs = (const float*)d_in[base + 8];
    }
    const float* lng = (const float*)d_in[30];
    const float* lnb = (const float*)d_in[31];

    // Workspace: ~104 MB
    char* ws = (char*)d_ws;
    size_t off = 0;
    auto alloc = [&](size_t bytes) { void* pp = ws + off; off += (bytes + 255) & ~(size_t)255; return pp; };
    int*   rowptr   = (int*)  alloc((NNODES + 1) * 4);
    int*   cursor   = (int*)  alloc(NNODES * 4);
    int*   deg      = (int*)  alloc(NNODES * 4);
    int*   blocksum = (int*)  alloc(256 * 4);
    int*   blockoff = (int*)  alloc(256 * 4);
    int2*  csr2     = (int2*) alloc((size_t)NEDGES * 8);        // 6.4 MB
    bf16*  hbuf     = (bf16*) alloc((size_t)NNODES * 64 * 2);   // 6.4 MB
    u16*   xb       = (u16*)  alloc((size_t)NNODES * 128 * 2);  // 12.8 MB bf16 x
    bf16*  comb     = (bf16*) alloc((size_t)NNODES * CW * 2);   // 38.4 MB: q|qwe|skip
    bf16*  vbuf     = (bf16*) alloc((size_t)NNODES * 256 * 2);  // 25.6 MB: v (512-B rows)
    u8*    k8       = (u8*)   alloc((size_t)NNODES * 256);      // 12.8 MB fp8 k
    bf16*  Wc       = (bf16*) alloc((size_t)NTOT * 128 * 2);    // 229 KB
    float* b896     = (float*)alloc(NTOT * 4);
    (void)ws_size;

    const int* srcArr = eidx;           // edge_index[0]
    const int* dstArr = eidx + NEDGES;  // edge_index[1]

    // CSR build (multi-block scan) + x cast
    int NB = (NNODES + 255) / 256;
    (void)hipMemsetAsync(deg, 0, NNODES * 4, stream);
    hist_kernel<<<(NEDGES + 255) / 256, 256, 0, stream>>>(dstArr, deg, NEDGES);
    scanA<<<NB, 256, 0, stream>>>(deg, cursor, blocksum, NNODES);
    scanB<<<1, 256, 0, stream>>>(blocksum, blockoff, NB, rowptr, NNODES);
    scanC<<<NB, 256, 0, stream>>>(deg, cursor, blockoff, rowptr, cursor, NNODES);
    scatter_kernel<<<(NEDGES + 255) / 256, 256, 0, stream>>>(srcArr, dstArr, cursor, csr2, NEDGES);
    xcast<<<(NNODES * 128 / 8 + 255) / 256, 256, 0, stream>>>(x, xb);

    int NBY = (NNODES + 255) / 256;   // 196 m-slabs of 256 rows
    int fins[3] = {128, 64, 64};

    const u16* hin = xb;
    for (int l = 0; l < 3; l++) {
        int FIN = fins[l];
        pack_all<<<NTOT, FIN, 0, stream>>>(p[l].Wq, p[l].bq, p[l].Wk, p[l].bk,
                                           p[l].Wv, p[l].bv, p[l].We, p[l].Ws, p[l].bs,
                                           Wc, b896, FIN);
        if (l == 0) gemm_v4<128><<<dim3(14, NBY), 256, 0, stream>>>(hin, Wc, b896, comb, vbuf, k8);
        else        gemm_v4<64> <<<dim3(14, NBY), 256, 0, stream>>>(hin, Wc, b896, comb, vbuf, k8);
        node_fused<<<NNODES / 4, 256, 0, stream>>>(rowptr, csr2, eattr, (const u16*)comb,
            (const u16*)vbuf, k8, p[l].We, lng, lnb,
            (l == 2) ? nullptr : hbuf, (l == 2) ? (float*)d_out : nullptr);
        hin = (const u16*)hbuf;
    }
}